// Round 1
// baseline (244.456 us; speedup 1.0000x reference)
//
#include <hip/hip_runtime.h>

typedef _Float16 f16;
typedef _Float16 f16x8 __attribute__((ext_vector_type(8)));
typedef float f32x4 __attribute__((ext_vector_type(4)));

// async global->LDS, 16B per lane; LDS dest = wave-uniform base + lane*16
#define GLD16(g, l) __builtin_amdgcn_global_load_lds( \
    (const __attribute__((address_space(1))) void*)(g), \
    (__attribute__((address_space(3))) void*)(l), 16, 0, 0)

// ---------------------------------------------------------------------------
// Generic f16 MFMA GEMM, BK=64: C[m][n] = sum_k A[m][k]*B[n][k] (+bias)
// A: [M][K] f16 row-major, B: [N][K] f16 row-major (B^T layout).
// MODE: 0 none, 1 bias[col], 2 bias[row], 3 split-QK (col<768 -> C else C2).
// 256 threads = 4 waves (2x2); wave tile (BM/2)x(BN/2); MFMA 16x16x32_f16,
// two k-groups per K-step. Two-barrier single-buffer K-loop (graph-replay-
// safe, R1/R2/R4-proven). LDS row = 64 f16 = 128 B; XOR swizzle: slot s of
// row r holds global chunk s^(r&7) -> ds_read_b128 perfectly bank-spread
// (2 lanes per 4-bank group per quad). Staging: one GLD16 issue = 8 rows,
// lane -> row lane>>3, slot lane&7, source chunk (lane&7)^(lane>>3).
// MINW = min waves/EU (VGPR cap): big-acc variants need 2.
// ---------------------------------------------------------------------------
template <typename OutT, int BM, int BN, int MODE, int MINW>
__global__ __launch_bounds__(256, MINW)
void gemm_kernel(const f16* __restrict__ A, long sA,
                 const f16* __restrict__ B, long sB,
                 void* __restrict__ Cv, long sC,
                 void* __restrict__ C2v,
                 const float* __restrict__ bias,
                 const float* __restrict__ bias2,
                 int N, int K)
{
    constexpr int FM = BM / 32;   // A-frags per wave (= (BM/2)/16)
    constexpr int FN = BN / 32;
    constexpr int IA = BM / 32;   // A staging issues per wave (= (BM/4)/8)
    constexpr int IB = BN / 32;

    OutT* C  = (OutT*)Cv;
    OutT* C2 = (OutT*)C2v;
    const int tid  = threadIdx.x;
    const int wave = tid >> 6;
    const int lane = tid & 63;
    const int bz   = blockIdx.z;
    A += (long)bz * sA;
    B += (long)bz * sB;
    C += (long)bz * sC;
    const long bm = (long)blockIdx.x * BM;
    const long bn = (long)blockIdx.y * BN;

    __shared__ f16 sAt[BM * 64];
    __shared__ f16 sBt[BN * 64];

    // staging lane map
    const int srow = lane >> 3;                       // 0..7
    const int gch  = ((lane & 7) ^ srow) * 8;         // source chunk (f16 off)

    const f16* gAb = A + (bm + wave * (BM / 4) + srow) * (long)K + gch;
    const f16* gBb = B + (bn + wave * (BN / 4) + srow) * (long)K + gch;

    const int wm = (wave >> 1) * (BM / 2);
    const int wn = (wave & 1) * (BN / 2);
    const int lr = lane & 15;
    const int qd = lane >> 4;
    // reader swizzle per k-group h: slot = (h*4+qd) ^ (lr&7)
    const int swz0 = ((0 * 4 + qd) ^ (lr & 7)) * 8;
    const int swz1 = ((1 * 4 + qd) ^ (lr & 7)) * 8;

    f32x4 acc[FM][FN] = {};

    for (int k0 = 0; k0 < K; k0 += 64) {
        #pragma unroll
        for (int i = 0; i < IA; ++i)
            GLD16(gAb + k0 + (long)i * 8 * K, &sAt[(wave * (BM / 4) + i * 8) * 64]);
        #pragma unroll
        for (int i = 0; i < IB; ++i)
            GLD16(gBb + k0 + (long)i * 8 * K, &sBt[(wave * (BN / 4) + i * 8) * 64]);
        __syncthreads();

        #pragma unroll
        for (int h = 0; h < 2; ++h) {
            const int swz = h ? swz1 : swz0;
            f16x8 af[FM], bf[FN];
            #pragma unroll
            for (int t = 0; t < FM; ++t)
                af[t] = *(const f16x8*)&sAt[(wm + t * 16 + lr) * 64 + swz];
            #pragma unroll
            for (int t = 0; t < FN; ++t)
                bf[t] = *(const f16x8*)&sBt[(wn + t * 16 + lr) * 64 + swz];
            #pragma unroll
            for (int tm = 0; tm < FM; ++tm)
                #pragma unroll
                for (int tn = 0; tn < FN; ++tn)
                    acc[tm][tn] = __builtin_amdgcn_mfma_f32_16x16x32_f16(
                        af[tm], bf[tn], acc[tm][tn], 0, 0, 0);
        }
        __syncthreads();
    }

    // epilogue: C/D layout col = lane&15, row = (lane>>4)*4 + reg
    #pragma unroll
    for (int tn = 0; tn < FN; ++tn) {
        const long col = bn + wn + tn * 16 + lr;
        OutT* dst = C;
        long cc = col, stride = N;
        float bc = 0.f;
        if (MODE == 1) bc = bias[col];
        if (MODE == 3) {
            stride = 768;
            if (col >= 768) { dst = C2; cc = col - 768; bc = bias2[cc]; }
            else            { bc = bias[cc]; }
        }
        #pragma unroll
        for (int tm = 0; tm < FM; ++tm) {
            #pragma unroll
            for (int r = 0; r < 4; ++r) {
                const long row = bm + wm + tm * 16 + qd * 4 + r;
                float v = acc[tm][tn][r] + bc;
                if (MODE == 2) v += bias[row];
                dst[row * stride + cc] = (OutT)v;
            }
        }
    }
}

// ---------------------------------------------------------------------------
// Pipelined 256x256 GEMM (f16 out, no bias), BK=64, 512 threads = 8 waves
// (2M x 4N, wave tile 128x64, acc[8][4]). Double-buffered LDS (128 KiB):
// per K-step, issue ALL 16 GLD16 for tile t+1 FIRST, then compute tile t,
// then one __syncthreads() (its compiler-emitted vmcnt(0)+lgkmcnt(0) drain
// is covered by the full tile of MFMA -> staging latency hidden, one
// barrier per K-step instead of two). Same proven XOR chunk swizzle as
// gemm_kernel. s_setprio(1) around MFMA clusters (waves drift across
// rh/h phases within a tile -> scheduler has roles to arbitrate).
// Used for S = Q K^T: grid 8x8x4 = 256 blocks = exactly 1 block/CU.
// ---------------------------------------------------------------------------
__global__ __launch_bounds__(512, 2)
void gemm_pipe(const f16* __restrict__ A, long sA,
               const f16* __restrict__ B, long sB,
               f16* __restrict__ C, long sC,
               int N, int K)
{
    const int tid  = threadIdx.x;
    const int wave = tid >> 6;
    const int lane = tid & 63;
    const int bz   = blockIdx.z;
    A += (long)bz * sA;
    B += (long)bz * sB;
    C += (long)bz * sC;
    const long bm = (long)blockIdx.x * 256;
    const long bn = (long)blockIdx.y * 256;

    __shared__ f16 sAt[2][256 * 64];   // 32 KiB x2
    __shared__ f16 sBt[2][256 * 64];   // 32 KiB x2

    // staging: wave w covers rows w*32 .. w*32+31 (4 GLD16 of 8 rows each)
    const int srow = lane >> 3;
    const int gch  = ((lane & 7) ^ srow) * 8;
    const f16* gA = A + (bm + wave * 32 + srow) * (long)K + gch;
    const f16* gB = B + (bn + wave * 32 + srow) * (long)K + gch;

    const int wm = (wave >> 2) * 128;   // 2 wave-rows
    const int wn = (wave & 3) * 64;     // 4 wave-cols
    const int lr = lane & 15;
    const int qd = lane >> 4;
    const int swz0 = ((0 * 4 + qd) ^ (lr & 7)) * 8;
    const int swz1 = ((1 * 4 + qd) ^ (lr & 7)) * 8;

    f32x4 acc[8][4] = {};

    // prologue: stage tile 0 into buffer 0
    #pragma unroll
    for (int i = 0; i < 4; ++i)
        GLD16(gA + (long)i * 8 * K, &sAt[0][(wave * 32 + i * 8) * 64]);
    #pragma unroll
    for (int i = 0; i < 4; ++i)
        GLD16(gB + (long)i * 8 * K, &sBt[0][(wave * 32 + i * 8) * 64]);
    __syncthreads();

    const int nt = K / 64;
    for (int t = 0; t < nt; ++t) {
        const int cur = t & 1;
        // issue next tile's staging early (into the other buffer)
        if (t + 1 < nt) {
            const long off = (long)(t + 1) * 64;
            #pragma unroll
            for (int i = 0; i < 4; ++i)
                GLD16(gA + off + (long)i * 8 * K, &sAt[cur ^ 1][(wave * 32 + i * 8) * 64]);
            #pragma unroll
            for (int i = 0; i < 4; ++i)
                GLD16(gB + off + (long)i * 8 * K, &sBt[cur ^ 1][(wave * 32 + i * 8) * 64]);
        }
        // compute current tile
        #pragma unroll
        for (int h = 0; h < 2; ++h) {
            const int swz = h ? swz1 : swz0;
            f16x8 bf[4];
            #pragma unroll
            for (int c = 0; c < 4; ++c)
                bf[c] = *(const f16x8*)&sBt[cur][(wn + c * 16 + lr) * 64 + swz];
            #pragma unroll
            for (int rh = 0; rh < 2; ++rh) {
                f16x8 af[4];
                #pragma unroll
                for (int m = 0; m < 4; ++m)
                    af[m] = *(const f16x8*)&sAt[cur][(wm + rh * 64 + m * 16 + lr) * 64 + swz];
                __builtin_amdgcn_s_setprio(1);
                #pragma unroll
                for (int m = 0; m < 4; ++m)
                    #pragma unroll
                    for (int c = 0; c < 4; ++c)
                        acc[rh * 4 + m][c] = __builtin_amdgcn_mfma_f32_16x16x32_f16(
                            af[m], bf[c], acc[rh * 4 + m][c], 0, 0, 0);
                __builtin_amdgcn_s_setprio(0);
            }
        }
        // single barrier per K-step: drains this wave's prefetch (covered by
        // the compute above) and fences buffer swap for all waves.
        __syncthreads();
    }

    // epilogue: col = lane&15, row = (lane>>4)*4 + reg
    #pragma unroll
    for (int cf = 0; cf < 4; ++cf) {
        const long col = bn + wn + cf * 16 + lr;
        #pragma unroll
        for (int rf = 0; rf < 8; ++rf) {
            #pragma unroll
            for (int r = 0; r < 4; ++r) {
                const long row = bm + wm + rf * 16 + qd * 4 + r;
                C[row * (long)N + col] = (f16)acc[rf][cf][r];
            }
        }
    }
}

// ---------------------------------------------------------------------------
// In-place row softmax over f16 scores; one block per row of 2048.
// fp32 math, unscaled (faithful to reference). Proven in R1/R2.
// ---------------------------------------------------------------------------
__global__ __launch_bounds__(256)
void softmax_kernel(f16* __restrict__ S)
{
    const long row = blockIdx.x;
    f16* p = S + row * 2048;
    const int tid  = threadIdx.x;
    const int wave = tid >> 6;
    const int lane = tid & 63;

    f16x8 x = *(const f16x8*)&p[tid * 8];
    float v[8];
    float m = -1e30f;
    #pragma unroll
    for (int j = 0; j < 8; ++j) { v[j] = (float)x[j]; m = fmaxf(m, v[j]); }
    #pragma unroll
    for (int off = 32; off > 0; off >>= 1) m = fmaxf(m, __shfl_down(m, off));

    __shared__ float rm[4], rs[4];
    if (lane == 0) rm[wave] = m;
    __syncthreads();
    m = fmaxf(fmaxf(rm[0], rm[1]), fmaxf(rm[2], rm[3]));

    float s = 0.f;
    #pragma unroll
    for (int j = 0; j < 8; ++j) { v[j] = __expf(v[j] - m); s += v[j]; }
    #pragma unroll
    for (int off = 32; off > 0; off >>= 1) s += __shfl_down(s, off);
    if (lane == 0) rs[wave] = s;
    __syncthreads();
    s = rs[0] + rs[1] + rs[2] + rs[3];
    const float inv = 1.0f / s;

    f16x8 y;
    #pragma unroll
    for (int j = 0; j < 8; ++j) y[j] = (f16)(v[j] * inv);
    *(f16x8*)&p[tid * 8] = y;
}

// ---------------------------------------------------------------------------
// fused fp32 -> f16 convert: blocks [0,3072) do x (6.29M elems),
// blocks [3072, 4224) do the 4 weight matrices (589824 elems each).
// ---------------------------------------------------------------------------
__global__ __launch_bounds__(256)
void cvt_all_kernel(const float* __restrict__ x,
                    const float* __restrict__ w0, const float* __restrict__ w1,
                    const float* __restrict__ w2, const float* __restrict__ w3,
                    f16* __restrict__ x16, f16* __restrict__ w16)
{
    const float* in; f16* out; long i;
    if (blockIdx.x < 3072) {
        in = x; out = x16;
        i = ((long)blockIdx.x * 256 + threadIdx.x) * 8;
    } else {
        const int wb  = blockIdx.x - 3072;          // 0..1151
        const int sel = wb / 288;                   // 288 blocks per weight
        in  = (sel == 0) ? w0 : (sel == 1) ? w1 : (sel == 2) ? w2 : w3;
        out = w16 + (long)sel * 589824;
        i = ((long)(wb - sel * 288) * 256 + threadIdx.x) * 8;
    }
    float4 a = *(const float4*)(in + i);
    float4 b = *(const float4*)(in + i + 4);
    f16x8 o;
    o[0] = (f16)a.x; o[1] = (f16)a.y; o[2] = (f16)a.z; o[3] = (f16)a.w;
    o[4] = (f16)b.x; o[5] = (f16)b.y; o[6] = (f16)b.z; o[7] = (f16)b.w;
    *(f16x8*)&out[i] = o;
}

// ---------------------------------------------------------------------------
// B=4, S=2048, D=H=768.  ws layout (bytes):
//   x16 @0  (12.6MB) | w16 @12582912 (4.7MB: wq,wk,wv,wo) | Q @17301504
//   K @29884416 | VT @42467328 ([4][768][2048]) | S @55050240 (33.5MB)
//   Y @88604672      total ~101 MB
// ---------------------------------------------------------------------------
extern "C" void kernel_launch(void* const* d_in, const int* in_sizes, int n_in,
                              void* d_out, int out_size, void* d_ws, size_t ws_size,
                              hipStream_t stream)
{
    const float* x  = (const float*)d_in[0];
    const float* wq = (const float*)d_in[1];
    const float* bq = (const float*)d_in[2];
    const float* wk = (const float*)d_in[3];
    const float* bk = (const float*)d_in[4];
    const float* wv = (const float*)d_in[5];
    const float* bv = (const float*)d_in[6];
    const float* wo = (const float*)d_in[7];
    const float* bo = (const float*)d_in[8];

    char* ws = (char*)d_ws;
    f16* x16 = (f16*)(ws + 0);
    f16* w16 = (f16*)(ws + 12582912);
    f16* Q   = (f16*)(ws + 17301504);
    f16* Kb  = (f16*)(ws + 29884416);
    f16* VT  = (f16*)(ws + 42467328);
    f16* S   = (f16*)(ws + 55050240);
    f16* Y   = (f16*)(ws + 88604672);

    f16* wv16 = w16 + 2 * 589824;
    f16* wo16 = w16 + 3 * 589824;

    cvt_all_kernel<<<4224, 256, 0, stream>>>(x, wq, wk, wv, wo, x16, w16);

    // fused Q|K projection: B = [wq;wk], N=1536, split outputs (768 blocks)
    gemm_kernel<f16, 128, 128, 3, 3><<<dim3(64, 12, 1), 256, 0, stream>>>(
        x16, 0, w16, 0, Q, 0, Kb, bq, bk, 1536, 768);
    // VT[b][h][s] = sum_d wv[h][d] x[b][s][d] + bv[h]  (row-bias; retiled
    // 128x128: 2x MFMA:stage ratio vs 64x128, 384 blocks)
    gemm_kernel<f16, 128, 128, 2, 3><<<dim3(6, 16, 4), 256, 0, stream>>>(
        wv16, 0, x16, (long)2048 * 768, VT, (long)768 * 2048, nullptr,
        bv, nullptr, 2048, 768);
    // S[b] = Q[b] @ K[b]^T : pipelined 256x256, 8x8x4 = 256 blocks = 1/CU
    gemm_pipe<<<dim3(8, 8, 4), 512, 0, stream>>>(
        Q, (long)2048 * 768, Kb, (long)2048 * 768, S, (long)2048 * 2048,
        2048, 768);
    softmax_kernel<<<8192, 256, 0, stream>>>(S);
    // Y[b] = P[b] @ V[b]: A = S, B = VT. 128x128 tiles (halves A-panel
    // re-reads vs 128x64: ~600->~400MB L2/L3 refetch; 384 blocks, K=2048)
    gemm_kernel<f16, 128, 128, 0, 3><<<dim3(16, 6, 4), 256, 0, stream>>>(
        S, (long)2048 * 2048, VT, (long)768 * 2048, Y, (long)2048 * 768,
        nullptr, nullptr, nullptr, 768, 2048);
    // out = Y @ wo^T + bo (fp32 out, 128x128, 384 blocks)
    gemm_kernel<float, 128, 128, 1, 3><<<dim3(64, 6, 1), 256, 0, stream>>>(
        Y, 0, wo16, 0, (float*)d_out, 0, nullptr, bo, nullptr, 768, 768);
}

// Round 2
// 230.200 us; speedup vs baseline: 1.0619x; 1.0619x over previous
//
#include <hip/hip_runtime.h>

typedef _Float16 f16;
typedef _Float16 f16x8 __attribute__((ext_vector_type(8)));
typedef float f32x4 __attribute__((ext_vector_type(4)));

// async global->LDS, 16B per lane; LDS dest = wave-uniform base + lane*16
#define GLD16(g, l) __builtin_amdgcn_global_load_lds( \
    (const __attribute__((address_space(1))) void*)(g), \
    (__attribute__((address_space(3))) void*)(l), 16, 0, 0)

// ---------------------------------------------------------------------------
// Generic f16 MFMA GEMM, BK=64: C[m][n] = sum_k A[m][k]*B[n][k] (+bias)
// A: [M][K] f16 row-major, B: [N][K] f16 row-major (B^T layout).
// MODE: 0 none, 1 bias[col], 2 bias[row], 3 split-QK (col<768 -> C else C2).
// 256 threads = 4 waves (2x2); wave tile (BM/2)x(BN/2); MFMA 16x16x32_f16,
// two k-groups per K-step. Two-barrier single-buffer K-loop (R0-proven).
// LDS row = 64 f16 = 128 B; XOR swizzle: slot s of row r holds global chunk
// s^(r&7) -> ds_read_b128 bank-spread. Staging: one GLD16 issue = 8 rows.
// ---------------------------------------------------------------------------
template <typename OutT, int BM, int BN, int MODE, int MINW>
__global__ __launch_bounds__(256, MINW)
void gemm_kernel(const f16* __restrict__ A, long sA,
                 const f16* __restrict__ B, long sB,
                 void* __restrict__ Cv, long sC,
                 void* __restrict__ C2v,
                 const float* __restrict__ bias,
                 const float* __restrict__ bias2,
                 int N, int K)
{
    constexpr int FM = BM / 32;
    constexpr int FN = BN / 32;
    constexpr int IA = BM / 32;
    constexpr int IB = BN / 32;

    OutT* C  = (OutT*)Cv;
    OutT* C2 = (OutT*)C2v;
    const int tid  = threadIdx.x;
    const int wave = tid >> 6;
    const int lane = tid & 63;
    const int bz   = blockIdx.z;
    A += (long)bz * sA;
    B += (long)bz * sB;
    C += (long)bz * sC;
    const long bm = (long)blockIdx.x * BM;
    const long bn = (long)blockIdx.y * BN;

    __shared__ f16 sAt[BM * 64];
    __shared__ f16 sBt[BN * 64];

    const int srow = lane >> 3;
    const int gch  = ((lane & 7) ^ srow) * 8;

    const f16* gAb = A + (bm + wave * (BM / 4) + srow) * (long)K + gch;
    const f16* gBb = B + (bn + wave * (BN / 4) + srow) * (long)K + gch;

    const int wm = (wave >> 1) * (BM / 2);
    const int wn = (wave & 1) * (BN / 2);
    const int lr = lane & 15;
    const int qd = lane >> 4;
    const int swz0 = ((0 * 4 + qd) ^ (lr & 7)) * 8;
    const int swz1 = ((1 * 4 + qd) ^ (lr & 7)) * 8;

    f32x4 acc[FM][FN] = {};

    for (int k0 = 0; k0 < K; k0 += 64) {
        #pragma unroll
        for (int i = 0; i < IA; ++i)
            GLD16(gAb + k0 + (long)i * 8 * K, &sAt[(wave * (BM / 4) + i * 8) * 64]);
        #pragma unroll
        for (int i = 0; i < IB; ++i)
            GLD16(gBb + k0 + (long)i * 8 * K, &sBt[(wave * (BN / 4) + i * 8) * 64]);
        __syncthreads();

        #pragma unroll
        for (int h = 0; h < 2; ++h) {
            const int swz = h ? swz1 : swz0;
            f16x8 af[FM], bf[FN];
            #pragma unroll
            for (int t = 0; t < FM; ++t)
                af[t] = *(const f16x8*)&sAt[(wm + t * 16 + lr) * 64 + swz];
            #pragma unroll
            for (int t = 0; t < FN; ++t)
                bf[t] = *(const f16x8*)&sBt[(wn + t * 16 + lr) * 64 + swz];
            #pragma unroll
            for (int tm = 0; tm < FM; ++tm)
                #pragma unroll
                for (int tn = 0; tn < FN; ++tn)
                    acc[tm][tn] = __builtin_amdgcn_mfma_f32_16x16x32_f16(
                        af[tm], bf[tn], acc[tm][tn], 0, 0, 0);
        }
        __syncthreads();
    }

    #pragma unroll
    for (int tn = 0; tn < FN; ++tn) {
        const long col = bn + wn + tn * 16 + lr;
        OutT* dst = C;
        long cc = col, stride = N;
        float bc = 0.f;
        if (MODE == 1) bc = bias[col];
        if (MODE == 3) {
            stride = 768;
            if (col >= 768) { dst = C2; cc = col - 768; bc = bias2[cc]; }
            else            { bc = bias[cc]; }
        }
        #pragma unroll
        for (int tm = 0; tm < FM; ++tm) {
            #pragma unroll
            for (int r = 0; r < 4; ++r) {
                const long row = bm + wm + tm * 16 + qd * 4 + r;
                float v = acc[tm][tn][r] + bc;
                if (MODE == 2) v += bias[row];
                dst[row * stride + cc] = (OutT)v;
            }
        }
    }
}

// ---------------------------------------------------------------------------
// COUNTED-VMCNT double-buffered 4-wave GEMM (T3-min + T4). Per K-step:
//   issue L(t+1) (IA+IB GLD16) -> buf[t+1&1]
//   s_waitcnt vmcnt(IA+IB)   // own L(t) retired; L(t+1) stays IN FLIGHT
//   raw s_barrier            // => all waves' L(t) retired -> tile t ready
//   compute(t) from buf[t&1] // covers L(t+1)'s HBM latency
//   raw s_barrier            // readers of buf[t&1] done before L(t+2) writes
// Raw barriers (no compiler vmcnt(0) drain) are safe: every cross-wave RAW
// is ordered by own-vmcnt-then-barrier; every WAR by the second barrier.
// Hazard note: no VGPR spills allowed in-loop (scratch ops would corrupt the
// vmcnt count) -- acc is small (FM*FN*4 regs), MINW=4 keeps cap at 128.
// 48 KiB LDS (dbuf) -> still 3 blocks/CU for 128x64 / 64x128 shapes.
// ---------------------------------------------------------------------------
template <typename OutT, int BM, int BN, int MODE, int MINW>
__global__ __launch_bounds__(256, MINW)
void gemm_pipe4(const f16* __restrict__ A, long sA,
                const f16* __restrict__ B, long sB,
                void* __restrict__ Cv, long sC,
                void* __restrict__ C2v,
                const float* __restrict__ bias,
                const float* __restrict__ bias2,
                int N, int K)
{
    constexpr int FM = BM / 32;
    constexpr int FN = BN / 32;
    constexpr int IA = BM / 32;
    constexpr int IB = BN / 32;

    OutT* C  = (OutT*)Cv;
    OutT* C2 = (OutT*)C2v;
    const int tid  = threadIdx.x;
    const int wave = tid >> 6;
    const int lane = tid & 63;
    const int bz   = blockIdx.z;
    A += (long)bz * sA;
    B += (long)bz * sB;
    C += (long)bz * sC;
    const long bm = (long)blockIdx.x * BM;
    const long bn = (long)blockIdx.y * BN;

    __shared__ f16 sAt[2][BM * 64];
    __shared__ f16 sBt[2][BN * 64];

    const int srow = lane >> 3;
    const int gch  = ((lane & 7) ^ srow) * 8;

    const f16* gAb = A + (bm + wave * (BM / 4) + srow) * (long)K + gch;
    const f16* gBb = B + (bn + wave * (BN / 4) + srow) * (long)K + gch;

    const int wm = (wave >> 1) * (BM / 2);
    const int wn = (wave & 1) * (BN / 2);
    const int lr = lane & 15;
    const int qd = lane >> 4;
    const int swz0 = ((0 * 4 + qd) ^ (lr & 7)) * 8;
    const int swz1 = ((1 * 4 + qd) ^ (lr & 7)) * 8;

    f32x4 acc[FM][FN] = {};

    // prologue: stage tile 0 (latency exposed once)
    #pragma unroll
    for (int i = 0; i < IA; ++i)
        GLD16(gAb + (long)i * 8 * K, &sAt[0][(wave * (BM / 4) + i * 8) * 64]);
    #pragma unroll
    for (int i = 0; i < IB; ++i)
        GLD16(gBb + (long)i * 8 * K, &sBt[0][(wave * (BN / 4) + i * 8) * 64]);

    const int nt = K / 64;
    for (int t = 0; t < nt; ++t) {
        const int cur = t & 1;
        if (t + 1 < nt) {
            const long off = (long)(t + 1) * 64;
            #pragma unroll
            for (int i = 0; i < IA; ++i)
                GLD16(gAb + off + (long)i * 8 * K, &sAt[cur ^ 1][(wave * (BM / 4) + i * 8) * 64]);
            #pragma unroll
            for (int i = 0; i < IB; ++i)
                GLD16(gBb + off + (long)i * 8 * K, &sBt[cur ^ 1][(wave * (BN / 4) + i * 8) * 64]);
            asm volatile("s_waitcnt vmcnt(%0)" :: "n"(IA + IB));
        } else {
            asm volatile("s_waitcnt vmcnt(0)");
        }
        __builtin_amdgcn_s_barrier();

        #pragma unroll
        for (int h = 0; h < 2; ++h) {
            const int swz = h ? swz1 : swz0;
            f16x8 af[FM], bf[FN];
            #pragma unroll
            for (int t2 = 0; t2 < FM; ++t2)
                af[t2] = *(const f16x8*)&sAt[cur][(wm + t2 * 16 + lr) * 64 + swz];
            #pragma unroll
            for (int t2 = 0; t2 < FN; ++t2)
                bf[t2] = *(const f16x8*)&sBt[cur][(wn + t2 * 16 + lr) * 64 + swz];
            __builtin_amdgcn_s_setprio(1);
            #pragma unroll
            for (int tm = 0; tm < FM; ++tm)
                #pragma unroll
                for (int tn = 0; tn < FN; ++tn)
                    acc[tm][tn] = __builtin_amdgcn_mfma_f32_16x16x32_f16(
                        af[tm], bf[tn], acc[tm][tn], 0, 0, 0);
            __builtin_amdgcn_s_setprio(0);
        }
        __builtin_amdgcn_s_barrier();
    }

    #pragma unroll
    for (int tn = 0; tn < FN; ++tn) {
        const long col = bn + wn + tn * 16 + lr;
        OutT* dst = C;
        long cc = col, stride = N;
        float bc = 0.f;
        if (MODE == 1) bc = bias[col];
        if (MODE == 3) {
            stride = 768;
            if (col >= 768) { dst = C2; cc = col - 768; bc = bias2[cc]; }
            else            { bc = bias[cc]; }
        }
        #pragma unroll
        for (int tm = 0; tm < FM; ++tm) {
            #pragma unroll
            for (int r = 0; r < 4; ++r) {
                const long row = bm + wm + tm * 16 + qd * 4 + r;
                float v = acc[tm][tn][r] + bc;
                if (MODE == 2) v += bias[row];
                dst[row * stride + cc] = (OutT)v;
            }
        }
    }
}

// ---------------------------------------------------------------------------
// Pipelined 256x256 GEMM (f16 out, no bias), BK=64, 512 threads = 8 waves
// (2M x 4N, wave tile 128x64, acc[8][4]). Same counted-vmcnt raw-barrier
// schedule as gemm_pipe4, 8 GLD16/wave in flight (vmcnt(8)). 128 KiB LDS.
// Used for S = Q K^T: grid 8x8x4 = 256 blocks = exactly 1 block/CU.
// ---------------------------------------------------------------------------
__global__ __launch_bounds__(512, 2)
void gemm_pipe(const f16* __restrict__ A, long sA,
               const f16* __restrict__ B, long sB,
               f16* __restrict__ C, long sC,
               int N, int K)
{
    const int tid  = threadIdx.x;
    const int wave = tid >> 6;
    const int lane = tid & 63;
    const int bz   = blockIdx.z;
    A += (long)bz * sA;
    B += (long)bz * sB;
    C += (long)bz * sC;
    const long bm = (long)blockIdx.x * 256;
    const long bn = (long)blockIdx.y * 256;

    __shared__ f16 sAt[2][256 * 64];
    __shared__ f16 sBt[2][256 * 64];

    const int srow = lane >> 3;
    const int gch  = ((lane & 7) ^ srow) * 8;
    const f16* gA = A + (bm + wave * 32 + srow) * (long)K + gch;
    const f16* gB = B + (bn + wave * 32 + srow) * (long)K + gch;

    const int wm = (wave >> 2) * 128;
    const int wn = (wave & 3) * 64;
    const int lr = lane & 15;
    const int qd = lane >> 4;
    const int swz0 = ((0 * 4 + qd) ^ (lr & 7)) * 8;
    const int swz1 = ((1 * 4 + qd) ^ (lr & 7)) * 8;

    f32x4 acc[8][4] = {};

    #pragma unroll
    for (int i = 0; i < 4; ++i)
        GLD16(gA + (long)i * 8 * K, &sAt[0][(wave * 32 + i * 8) * 64]);
    #pragma unroll
    for (int i = 0; i < 4; ++i)
        GLD16(gB + (long)i * 8 * K, &sBt[0][(wave * 32 + i * 8) * 64]);

    const int nt = K / 64;
    for (int t = 0; t < nt; ++t) {
        const int cur = t & 1;
        if (t + 1 < nt) {
            const long off = (long)(t + 1) * 64;
            #pragma unroll
            for (int i = 0; i < 4; ++i)
                GLD16(gA + off + (long)i * 8 * K, &sAt[cur ^ 1][(wave * 32 + i * 8) * 64]);
            #pragma unroll
            for (int i = 0; i < 4; ++i)
                GLD16(gB + off + (long)i * 8 * K, &sBt[cur ^ 1][(wave * 32 + i * 8) * 64]);
            asm volatile("s_waitcnt vmcnt(8)");
        } else {
            asm volatile("s_waitcnt vmcnt(0)");
        }
        __builtin_amdgcn_s_barrier();

        #pragma unroll
        for (int h = 0; h < 2; ++h) {
            const int swz = h ? swz1 : swz0;
            f16x8 bf[4];
            #pragma unroll
            for (int c = 0; c < 4; ++c)
                bf[c] = *(const f16x8*)&sBt[cur][(wn + c * 16 + lr) * 64 + swz];
            #pragma unroll
            for (int rh = 0; rh < 2; ++rh) {
                f16x8 af[4];
                #pragma unroll
                for (int m = 0; m < 4; ++m)
                    af[m] = *(const f16x8*)&sAt[cur][(wm + rh * 64 + m * 16 + lr) * 64 + swz];
                __builtin_amdgcn_s_setprio(1);
                #pragma unroll
                for (int m = 0; m < 4; ++m)
                    #pragma unroll
                    for (int c = 0; c < 4; ++c)
                        acc[rh * 4 + m][c] = __builtin_amdgcn_mfma_f32_16x16x32_f16(
                            af[m], bf[c], acc[rh * 4 + m][c], 0, 0, 0);
                __builtin_amdgcn_s_setprio(0);
            }
        }
        __builtin_amdgcn_s_barrier();
    }

    #pragma unroll
    for (int cf = 0; cf < 4; ++cf) {
        const long col = bn + wn + cf * 16 + lr;
        #pragma unroll
        for (int rf = 0; rf < 8; ++rf) {
            #pragma unroll
            for (int r = 0; r < 4; ++r) {
                const long row = bm + wm + rf * 16 + qd * 4 + r;
                C[row * (long)N + col] = (f16)acc[rf][cf][r];
            }
        }
    }
}

// ---------------------------------------------------------------------------
// In-place row softmax over f16 scores; one block per row of 2048.
// ---------------------------------------------------------------------------
__global__ __launch_bounds__(256)
void softmax_kernel(f16* __restrict__ S)
{
    const long row = blockIdx.x;
    f16* p = S + row * 2048;
    const int tid  = threadIdx.x;
    const int wave = tid >> 6;
    const int lane = tid & 63;

    f16x8 x = *(const f16x8*)&p[tid * 8];
    float v[8];
    float m = -1e30f;
    #pragma unroll
    for (int j = 0; j < 8; ++j) { v[j] = (float)x[j]; m = fmaxf(m, v[j]); }
    #pragma unroll
    for (int off = 32; off > 0; off >>= 1) m = fmaxf(m, __shfl_down(m, off));

    __shared__ float rm[4], rs[4];
    if (lane == 0) rm[wave] = m;
    __syncthreads();
    m = fmaxf(fmaxf(rm[0], rm[1]), fmaxf(rm[2], rm[3]));

    float s = 0.f;
    #pragma unroll
    for (int j = 0; j < 8; ++j) { v[j] = __expf(v[j] - m); s += v[j]; }
    #pragma unroll
    for (int off = 32; off > 0; off >>= 1) s += __shfl_down(s, off);
    if (lane == 0) rs[wave] = s;
    __syncthreads();
    s = rs[0] + rs[1] + rs[2] + rs[3];
    const float inv = 1.0f / s;

    f16x8 y;
    #pragma unroll
    for (int j = 0; j < 8; ++j) y[j] = (f16)(v[j] * inv);
    *(f16x8*)&p[tid * 8] = y;
}

// ---------------------------------------------------------------------------
// fused fp32 -> f16 convert: blocks [0,3072) do x (6.29M elems),
// blocks [3072, 4224) do the 4 weight matrices (589824 elems each).
// ---------------------------------------------------------------------------
__global__ __launch_bounds__(256)
void cvt_all_kernel(const float* __restrict__ x,
                    const float* __restrict__ w0, const float* __restrict__ w1,
                    const float* __restrict__ w2, const float* __restrict__ w3,
                    f16* __restrict__ x16, f16* __restrict__ w16)
{
    const float* in; f16* out; long i;
    if (blockIdx.x < 3072) {
        in = x; out = x16;
        i = ((long)blockIdx.x * 256 + threadIdx.x) * 8;
    } else {
        const int wb  = blockIdx.x - 3072;
        const int sel = wb / 288;
        in  = (sel == 0) ? w0 : (sel == 1) ? w1 : (sel == 2) ? w2 : w3;
        out = w16 + (long)sel * 589824;
        i = ((long)(wb - sel * 288) * 256 + threadIdx.x) * 8;
    }
    float4 a = *(const float4*)(in + i);
    float4 b = *(const float4*)(in + i + 4);
    f16x8 o;
    o[0] = (f16)a.x; o[1] = (f16)a.y; o[2] = (f16)a.z; o[3] = (f16)a.w;
    o[4] = (f16)b.x; o[5] = (f16)b.y; o[6] = (f16)b.z; o[7] = (f16)b.w;
    *(f16x8*)&out[i] = o;
}

// ---------------------------------------------------------------------------
// B=4, S=2048, D=H=768.  ws layout (bytes):
//   x16 @0  (12.6MB) | w16 @12582912 (4.7MB: wq,wk,wv,wo) | Q @17301504
//   K @29884416 | VT @42467328 ([4][768][2048]) | S @55050240 (33.5MB)
//   Y @88604672      total ~101 MB
// ---------------------------------------------------------------------------
extern "C" void kernel_launch(void* const* d_in, const int* in_sizes, int n_in,
                              void* d_out, int out_size, void* d_ws, size_t ws_size,
                              hipStream_t stream)
{
    const float* x  = (const float*)d_in[0];
    const float* wq = (const float*)d_in[1];
    const float* bq = (const float*)d_in[2];
    const float* wk = (const float*)d_in[3];
    const float* bk = (const float*)d_in[4];
    const float* wv = (const float*)d_in[5];
    const float* bv = (const float*)d_in[6];
    const float* wo = (const float*)d_in[7];
    const float* bo = (const float*)d_in[8];

    char* ws = (char*)d_ws;
    f16* x16 = (f16*)(ws + 0);
    f16* w16 = (f16*)(ws + 12582912);
    f16* Q   = (f16*)(ws + 17301504);
    f16* Kb  = (f16*)(ws + 29884416);
    f16* VT  = (f16*)(ws + 42467328);
    f16* S   = (f16*)(ws + 55050240);
    f16* Y   = (f16*)(ws + 88604672);

    f16* wv16 = w16 + 2 * 589824;
    f16* wo16 = w16 + 3 * 589824;

    cvt_all_kernel<<<4224, 256, 0, stream>>>(x, wq, wk, wv, wo, x16, w16);

    // fused Q|K projection: 128x128 single-buffer (3 blocks/CU proven),
    // grid 64x12 = 768 blocks = 3/CU exact.
    gemm_kernel<f16, 128, 128, 3, 3><<<dim3(64, 12, 1), 256, 0, stream>>>(
        x16, 0, w16, 0, Q, 0, Kb, bq, bk, 1536, 768);
    // VT[b][h][s]: counted-pipe 64x128, 768 blocks = 3/CU (reverted shape).
    gemm_pipe4<f16, 64, 128, 2, 4><<<dim3(12, 16, 4), 256, 0, stream>>>(
        wv16, 0, x16, (long)2048 * 768, VT, (long)768 * 2048, nullptr,
        bv, nullptr, 2048, 768);
    // S[b] = Q[b] @ K[b]^T : counted-pipe 256x256, 256 blocks = 1/CU.
    gemm_pipe<<<dim3(8, 8, 4), 512, 0, stream>>>(
        Q, (long)2048 * 768, Kb, (long)2048 * 768, S, (long)2048 * 2048,
        2048, 768);
    softmax_kernel<<<8192, 256, 0, stream>>>(S);
    // Y[b] = P[b] @ V[b]: counted-pipe 128x64, 768 blocks = 3/CU, K=2048.
    gemm_pipe4<f16, 128, 64, 0, 4><<<dim3(16, 12, 4), 256, 0, stream>>>(
        S, (long)2048 * 2048, VT, (long)768 * 2048, Y, (long)2048 * 768,
        nullptr, nullptr, nullptr, 768, 2048);
    // out = Y @ wo^T + bo: counted-pipe 128x64, 768 blocks = 3/CU.
    gemm_pipe4<float, 128, 64, 1, 4><<<dim3(64, 12, 1), 256, 0, stream>>>(
        Y, 0, wo16, 0, (float*)d_out, 0, nullptr, bo, nullptr, 768, 768);
}